// Round 4
// baseline (977.230 us; speedup 1.0000x reference)
//
#include <hip/hip_runtime.h>

#define FEAT 128
#define REP 8

// ---------------- degree count, XCD-local replicas (replica-major) ----------------
__global__ void degree8_kernel(const int* __restrict__ src, const int* __restrict__ dst,
                               int* __restrict__ degS, int* __restrict__ degD, int E, int n) {
    int e = blockIdx.x * blockDim.x + threadIdx.x;
    int r = blockIdx.x & 7;
    if (e < E) {
        atomicAdd(&degS[r * n + src[e]], 1);
        atomicAdd(&degD[r * n + dst[e]], 1);
    }
}

// ---------------- scan over node-major view of degD: j = v*8+r -> degD[r*n+v] ----------------
__global__ __launch_bounds__(256) void scan_partial8(const int* __restrict__ degD,
                                                     int* __restrict__ blockSums, int n, int nr) {
    __shared__ int buf[256];
    int tid = threadIdx.x;
    int base = blockIdx.x * 2048 + tid * 8;
    int s = 0;
    #pragma unroll
    for (int t = 0; t < 8; ++t) {
        int j = base + t;
        if (j < nr) s += degD[(j & 7) * n + (j >> 3)];
    }
    buf[tid] = s;
    __syncthreads();
    #pragma unroll
    for (int off = 1; off < 256; off <<= 1) {
        int t = (tid >= off) ? buf[tid - off] : 0;
        __syncthreads();
        buf[tid] += t;
        __syncthreads();
    }
    if (tid == 255) blockSums[blockIdx.x] = buf[255];
}

__global__ __launch_bounds__(256) void scan_blocksums(const int* __restrict__ blockSums,
                                                      int* __restrict__ blockOffs, int nb,
                                                      int* __restrict__ offs8, int nr) {
    __shared__ int buf[256];
    int tid = threadIdx.x;
    int v = (tid < nb) ? blockSums[tid] : 0;
    buf[tid] = v;
    __syncthreads();
    #pragma unroll
    for (int off = 1; off < 256; off <<= 1) {
        int t = (tid >= off) ? buf[tid - off] : 0;
        __syncthreads();
        buf[tid] += t;
        __syncthreads();
    }
    if (tid < nb) blockOffs[tid] = buf[tid] - v;
    if (tid == 255) offs8[nr] = buf[255];
}

__global__ __launch_bounds__(256) void scan_write8(const int* __restrict__ degD,
                                                   const int* __restrict__ blockOffs,
                                                   int* __restrict__ offs8, int n, int nr) {
    __shared__ int buf[256];
    int tid = threadIdx.x;
    int base = blockIdx.x * 2048 + tid * 8;
    int v[8];
    int s = 0;
    #pragma unroll
    for (int t = 0; t < 8; ++t) {
        int j = base + t;
        v[t] = (j < nr) ? degD[(j & 7) * n + (j >> 3)] : 0;
        s += v[t];
    }
    buf[tid] = s;
    __syncthreads();
    #pragma unroll
    for (int off = 1; off < 256; off <<= 1) {
        int t = (tid >= off) ? buf[tid - off] : 0;
        __syncthreads();
        buf[tid] += t;
        __syncthreads();
    }
    int o = blockOffs[blockIdx.x] + buf[tid] - s;
    #pragma unroll
    for (int t = 0; t < 8; ++t) {
        int j = base + t;
        if (j < nr) offs8[j] = o;
        o += v[t];
    }
}

// ---------------- norms + compact offsets + cursor init (cursor aliases degS) ----------------
__global__ void normc_kernel(int* __restrict__ degS_cur,   // read degS, then write cursor in-place
                             const int* __restrict__ offs8,
                             float* __restrict__ ns, float* __restrict__ nd,
                             int* __restrict__ offs_c, int n) {
    int v = blockIdx.x * blockDim.x + threadIdx.x;
    if (v >= n) return;
    int so = 0;
    #pragma unroll
    for (int r = 0; r < REP; ++r) so += degS_cur[r * n + v];
    int base = offs8[v * 8];
    int next = offs8[(v + 1) * 8];
    int si = next - base;
    ns[v] = 1.0f / sqrtf((float)(so < 1 ? 1 : so));
    nd[v] = 1.0f / sqrtf((float)(si < 1 ? 1 : si));
    offs_c[v] = base;
    if (v == 0) offs_c[n] = offs8[8 * n];
    #pragma unroll
    for (int r = 0; r < REP; ++r) degS_cur[r * n + v] = offs8[v * 8 + r];
}

// ---------------- CSR fill with XCD-local cursors ----------------
__global__ void fill8_kernel(const int* __restrict__ src, const int* __restrict__ dst,
                             const float* __restrict__ ns,
                             int* __restrict__ cursor, int* __restrict__ esrc,
                             float* __restrict__ ew, int E, int n) {
    int e = blockIdx.x * blockDim.x + threadIdx.x;
    int r = blockIdx.x & 7;
    if (e < E) {
        int s = src[e];
        int p = atomicAdd(&cursor[r * n + dst[e]], 1);
        esrc[p] = s;
        ew[p] = ns[s];
    }
}

// ---------------- fused aggregate + GEMM + bias + relu ----------------
// block = 256 threads = 4 waves, 64 nodes/block.
// Phase 1: each wave aggregates 16 nodes into LDS Ms[64][132] (full K resident).
// Phase 2: GEMM from LDS, W staged in 32-k chunks, 4x8 register blocking.
__global__ __launch_bounds__(256) void fused_kernel(const float* __restrict__ x,
                                                    const int* __restrict__ offs,
                                                    const int* __restrict__ esrc,
                                                    const float* __restrict__ ew,
                                                    const float* __restrict__ nd,
                                                    const float* __restrict__ W,
                                                    const float* __restrict__ bias,
                                                    float* __restrict__ out, int n) {
    __shared__ float Ms[64][132];   // stride 132: 16B-aligned rows, conflict-free b128 reads
    __shared__ float Ws[32][128];
    int tid = threadIdx.x;
    int lane = tid & 63;
    int wave = tid >> 6;
    int r0 = blockIdx.x * 64;

    // ---- phase 1: aggregation ----
    for (int i = 0; i < 16; ++i) {
        int row = wave * 16 + i;
        int v = r0 + row;
        if (v < n) {
            int s0 = offs[v], s1 = offs[v + 1];
            float ax0 = 0.f, ay0 = 0.f, ax1 = 0.f, ay1 = 0.f;
            float ax2 = 0.f, ay2 = 0.f, ax3 = 0.f, ay3 = 0.f;
            int j = s0;
            for (; j + 4 <= s1; j += 4) {
                int sa = esrc[j], sb = esrc[j + 1], sc = esrc[j + 2], sd = esrc[j + 3];
                float wa = ew[j], wb = ew[j + 1], wc = ew[j + 2], wd = ew[j + 3];
                float2 ta = ((const float2*)(x + (size_t)sa * FEAT))[lane];
                float2 tb = ((const float2*)(x + (size_t)sb * FEAT))[lane];
                float2 tc = ((const float2*)(x + (size_t)sc * FEAT))[lane];
                float2 td = ((const float2*)(x + (size_t)sd * FEAT))[lane];
                ax0 = fmaf(ta.x, wa, ax0); ay0 = fmaf(ta.y, wa, ay0);
                ax1 = fmaf(tb.x, wb, ax1); ay1 = fmaf(tb.y, wb, ay1);
                ax2 = fmaf(tc.x, wc, ax2); ay2 = fmaf(tc.y, wc, ay2);
                ax3 = fmaf(td.x, wd, ax3); ay3 = fmaf(td.y, wd, ay3);
            }
            for (; j < s1; ++j) {
                int s = esrc[j];
                float w = ew[j];
                float2 t = ((const float2*)(x + (size_t)s * FEAT))[lane];
                ax0 = fmaf(t.x, w, ax0); ay0 = fmaf(t.y, w, ay0);
            }
            float sc_ = nd[v];
            float2 rr;
            rr.x = ((ax0 + ax1) + (ax2 + ax3)) * sc_;
            rr.y = ((ay0 + ay1) + (ay2 + ay3)) * sc_;
            *(float2*)&Ms[row][2 * lane] = rr;
        }
    }
    __syncthreads();

    // ---- phase 2: GEMM ----
    int tx = tid & 15;
    int ty = tid >> 4;
    float acc[4][8];
    #pragma unroll
    for (int r = 0; r < 4; ++r)
        #pragma unroll
        for (int i = 0; i < 8; ++i) acc[r][i] = 0.f;

    for (int k0 = 0; k0 < FEAT; k0 += 32) {
        if (k0) __syncthreads();
        #pragma unroll
        for (int i = 0; i < 4; ++i) {
            int idx = tid + i * 256;
            ((float4*)&Ws[0][0])[idx] = ((const float4*)(W + (size_t)k0 * FEAT))[idx];
        }
        __syncthreads();
        #pragma unroll
        for (int kk = 0; kk < 32; kk += 4) {
            float4 a0 = *(const float4*)&Ms[ty * 4 + 0][k0 + kk];
            float4 a1 = *(const float4*)&Ms[ty * 4 + 1][k0 + kk];
            float4 a2 = *(const float4*)&Ms[ty * 4 + 2][k0 + kk];
            float4 a3 = *(const float4*)&Ms[ty * 4 + 3][k0 + kk];
            #pragma unroll
            for (int j2 = 0; j2 < 4; ++j2) {
                float4 w0 = *(const float4*)&Ws[kk + j2][tx * 4];
                float4 w1 = *(const float4*)&Ws[kk + j2][64 + tx * 4];
                float a[4] = { ((const float*)&a0)[j2], ((const float*)&a1)[j2],
                               ((const float*)&a2)[j2], ((const float*)&a3)[j2] };
                #pragma unroll
                for (int r = 0; r < 4; ++r) {
                    acc[r][0] = fmaf(a[r], w0.x, acc[r][0]);
                    acc[r][1] = fmaf(a[r], w0.y, acc[r][1]);
                    acc[r][2] = fmaf(a[r], w0.z, acc[r][2]);
                    acc[r][3] = fmaf(a[r], w0.w, acc[r][3]);
                    acc[r][4] = fmaf(a[r], w1.x, acc[r][4]);
                    acc[r][5] = fmaf(a[r], w1.y, acc[r][5]);
                    acc[r][6] = fmaf(a[r], w1.z, acc[r][6]);
                    acc[r][7] = fmaf(a[r], w1.w, acc[r][7]);
                }
            }
        }
    }

    float4 b0 = *(const float4*)&bias[tx * 4];
    float4 b1 = *(const float4*)&bias[64 + tx * 4];
    #pragma unroll
    for (int r = 0; r < 4; ++r) {
        int row = r0 + ty * 4 + r;
        if (row < n) {
            float4 v0, v1;
            v0.x = acc[r][0] + b0.x; v0.y = acc[r][1] + b0.y;
            v0.z = acc[r][2] + b0.z; v0.w = acc[r][3] + b0.w;
            v1.x = acc[r][4] + b1.x; v1.y = acc[r][5] + b1.y;
            v1.z = acc[r][6] + b1.z; v1.w = acc[r][7] + b1.w;
            v0.x = v0.x > 0.f ? v0.x : 0.f; v0.y = v0.y > 0.f ? v0.y : 0.f;
            v0.z = v0.z > 0.f ? v0.z : 0.f; v0.w = v0.w > 0.f ? v0.w : 0.f;
            v1.x = v1.x > 0.f ? v1.x : 0.f; v1.y = v1.y > 0.f ? v1.y : 0.f;
            v1.z = v1.z > 0.f ? v1.z : 0.f; v1.w = v1.w > 0.f ? v1.w : 0.f;
            *(float4*)(out + (size_t)row * FEAT + tx * 4) = v0;
            *(float4*)(out + (size_t)row * FEAT + 64 + tx * 4) = v1;
        }
    }
}

// ---------------- final: copy h5 -> out_h, threshold -> out_c (in-place on out_c) ----------------
__global__ void thresh_kernel(float* __restrict__ h5_c, float* __restrict__ out_h, int n4) {
    int i = blockIdx.x * blockDim.x + threadIdx.x;
    if (i < n4) {
        float4 v = ((const float4*)h5_c)[i];
        ((float4*)out_h)[i] = v;
        float4 c;
        c.x = v.x >= 0.5f ? 1.f : 0.f;
        c.y = v.y >= 0.5f ? 1.f : 0.f;
        c.z = v.z >= 0.5f ? 1.f : 0.f;
        c.w = v.w >= 0.5f ? 1.f : 0.f;
        ((float4*)h5_c)[i] = c;
    }
}

extern "C" void kernel_launch(void* const* d_in, const int* in_sizes, int n_in,
                              void* d_out, int out_size, void* d_ws, size_t ws_size,
                              hipStream_t stream) {
    const float* in_feat = (const float*)d_in[0];
    const int*   src     = (const int*)d_in[1];
    const int*   dst     = (const int*)d_in[2];
    const float* W[5] = {(const float*)d_in[3], (const float*)d_in[5], (const float*)d_in[7],
                         (const float*)d_in[9], (const float*)d_in[11]};
    const float* B[5] = {(const float*)d_in[4], (const float*)d_in[6], (const float*)d_in[8],
                         (const float*)d_in[10], (const float*)d_in[12]};
    const int E = in_sizes[1];
    const int N = in_sizes[0] / FEAT;
    const int NR = N * REP;

    // ---- workspace layout (all 16B-aligned) ----
    char* ws = (char*)d_ws;
    size_t off = 0;
    auto alloc = [&](size_t bytes) { size_t o = off; off += (bytes + 15) & ~size_t(15); return o; };
    int*   esrc      = (int*)  (ws + alloc((size_t)E * 4));
    float* ew        = (float*)(ws + alloc((size_t)E * 4));
    float* ns        = (float*)(ws + alloc((size_t)N * 4));
    float* nd        = (float*)(ws + alloc((size_t)N * 4));
    int*   offs_c    = (int*)  (ws + alloc((size_t)(N + 1) * 4));
    int*   blockSums = (int*)  (ws + alloc(1024));
    int*   blockOffs = (int*)  (ws + alloc(1024));
    size_t degS_off  = alloc((size_t)NR * 4);
    int*   degS      = (int*)(ws + degS_off);        // later reused as cursor
    int*   degD      = (int*)(ws + alloc((size_t)NR * 4));
    int*   offs8     = (int*)(ws + alloc((size_t)(NR + 1) * 4));

    float* out_h = (float*)d_out;
    float* out_c = out_h + (size_t)N * FEAT;

    hipMemsetAsync(ws + degS_off, 0, (size_t)NR * 8, stream);   // zero degS + degD (contiguous)

    const int eb = (E + 255) / 256;
    const int sb = (NR + 2047) / 2048;      // scan blocks (196 for N=50000)
    const int vb = (N + 255) / 256;

    degree8_kernel<<<eb, 256, 0, stream>>>(src, dst, degS, degD, E, N);
    scan_partial8<<<sb, 256, 0, stream>>>(degD, blockSums, N, NR);
    scan_blocksums<<<1, 256, 0, stream>>>(blockSums, blockOffs, sb, offs8, NR);
    scan_write8<<<sb, 256, 0, stream>>>(degD, blockOffs, offs8, N, NR);
    normc_kernel<<<vb, 256, 0, stream>>>(degS, offs8, ns, nd, offs_c, N);
    fill8_kernel<<<eb, 256, 0, stream>>>(src, dst, ns, degS /*cursor*/, esrc, ew, E, N);

    const int fb = (N + 63) / 64;
    // buffer ping-pong: L1->out_c, L2->out_h, L3->out_c, L4->out_h, L5->out_c
    fused_kernel<<<fb, 256, 0, stream>>>(in_feat, offs_c, esrc, ew, nd, W[0], B[0], out_c, N);
    fused_kernel<<<fb, 256, 0, stream>>>(out_c,   offs_c, esrc, ew, nd, W[1], B[1], out_h, N);
    fused_kernel<<<fb, 256, 0, stream>>>(out_h,   offs_c, esrc, ew, nd, W[2], B[2], out_c, N);
    fused_kernel<<<fb, 256, 0, stream>>>(out_c,   offs_c, esrc, ew, nd, W[3], B[3], out_h, N);
    fused_kernel<<<fb, 256, 0, stream>>>(out_h,   offs_c, esrc, ew, nd, W[4], B[4], out_c, N);

    const int n4 = N * FEAT / 4;
    thresh_kernel<<<(n4 + 255) / 256, 256, 0, stream>>>(out_c, out_h, n4);
}

// Round 5
// 715.480 us; speedup vs baseline: 1.3658x; 1.3658x over previous
//
#include <hip/hip_runtime.h>

#define FEAT 128
#define RANGE 4096
#define NSLICE 32

// ================= preprocessing (atomic-free) =================

// hist: block (s,r) counts src/dst in node range r over edge slice s (LDS atomics only)
__global__ __launch_bounds__(256) void hist_kernel(const int* __restrict__ src,
                                                   const int* __restrict__ dst,
                                                   int* __restrict__ partialS,
                                                   int* __restrict__ partialD,
                                                   int E, int n) {
    __shared__ int hs[RANGE];
    __shared__ int hd[RANGE];
    int tid = threadIdx.x;
    int s = blockIdx.x & (NSLICE - 1);
    int r = blockIdx.x >> 5;
    int v0 = r * RANGE;
    #pragma unroll
    for (int i = tid; i < RANGE; i += 256) { hs[i] = 0; hd[i] = 0; }
    __syncthreads();
    int e0 = (int)((long long)E * s / NSLICE);
    int e1 = (int)((long long)E * (s + 1) / NSLICE);
    for (int e = e0 + tid; e < e1; e += 256) {
        unsigned dd = (unsigned)(dst[e] - v0);
        if (dd < RANGE) atomicAdd(&hd[dd], 1);
        unsigned ss = (unsigned)(src[e] - v0);
        if (ss < RANGE) atomicAdd(&hs[ss], 1);
    }
    __syncthreads();
    for (int i = tid; i < RANGE; i += 256) {
        int v = v0 + i;
        if (v < n) {
            partialS[(size_t)s * n + v] = hs[i];
            partialD[(size_t)s * n + v] = hd[i];
        }
    }
}

// reduce: degrees + norms
__global__ void reduce_kernel(const int* __restrict__ partialS,
                              const int* __restrict__ partialD,
                              int* __restrict__ deg_in,
                              float* __restrict__ ns, float* __restrict__ nd, int n) {
    int v = blockIdx.x * blockDim.x + threadIdx.x;
    if (v >= n) return;
    int so = 0, si = 0;
    #pragma unroll
    for (int s = 0; s < NSLICE; ++s) {
        so += partialS[(size_t)s * n + v];
        si += partialD[(size_t)s * n + v];
    }
    deg_in[v] = si;
    ns[v] = 1.0f / sqrtf((float)(so < 1 ? 1 : so));
    nd[v] = 1.0f / sqrtf((float)(si < 1 ? 1 : si));
}

// 3-phase exclusive scan of deg_in -> offs
__global__ __launch_bounds__(256) void scan_partial(const int* __restrict__ deg,
                                                    int* __restrict__ blockSums, int n) {
    __shared__ int buf[256];
    int tid = threadIdx.x;
    int base = blockIdx.x * 1024 + tid * 4;
    int s = 0;
    #pragma unroll
    for (int j = 0; j < 4; ++j) {
        int idx = base + j;
        s += (idx < n) ? deg[idx] : 0;
    }
    buf[tid] = s;
    __syncthreads();
    #pragma unroll
    for (int off = 1; off < 256; off <<= 1) {
        int t = (tid >= off) ? buf[tid - off] : 0;
        __syncthreads();
        buf[tid] += t;
        __syncthreads();
    }
    if (tid == 255) blockSums[blockIdx.x] = buf[255];
}

__global__ __launch_bounds__(256) void scan_blocksums(const int* __restrict__ blockSums,
                                                      int* __restrict__ blockOffs, int nb,
                                                      int* __restrict__ offs, int n) {
    __shared__ int buf[256];
    int tid = threadIdx.x;
    int v = (tid < nb) ? blockSums[tid] : 0;
    buf[tid] = v;
    __syncthreads();
    #pragma unroll
    for (int off = 1; off < 256; off <<= 1) {
        int t = (tid >= off) ? buf[tid - off] : 0;
        __syncthreads();
        buf[tid] += t;
        __syncthreads();
    }
    if (tid < nb) blockOffs[tid] = buf[tid] - v;
    if (tid == 255) offs[n] = buf[255];
}

__global__ __launch_bounds__(256) void scan_write(const int* __restrict__ deg,
                                                  const int* __restrict__ blockOffs,
                                                  int* __restrict__ offs, int n) {
    __shared__ int buf[256];
    int tid = threadIdx.x;
    int base = blockIdx.x * 1024 + tid * 4;
    int v[4];
    int s = 0;
    #pragma unroll
    for (int j = 0; j < 4; ++j) {
        int idx = base + j;
        v[j] = (idx < n) ? deg[idx] : 0;
        s += v[j];
    }
    buf[tid] = s;
    __syncthreads();
    #pragma unroll
    for (int off = 1; off < 256; off <<= 1) {
        int t = (tid >= off) ? buf[tid - off] : 0;
        __syncthreads();
        buf[tid] += t;
        __syncthreads();
    }
    int o = blockOffs[blockIdx.x] + buf[tid] - s;
    #pragma unroll
    for (int j = 0; j < 4; ++j) {
        int idx = base + j;
        if (idx < n) offs[idx] = o;
        o += v[j];
    }
}

// convert per-slice counts -> per-slice base cursors (in-place on partialD)
__global__ void cursor_kernel(int* __restrict__ partialD, const int* __restrict__ offs, int n) {
    int v = blockIdx.x * blockDim.x + threadIdx.x;
    if (v >= n) return;
    int base = offs[v];
    #pragma unroll
    for (int s = 0; s < NSLICE; ++s) {
        int c = partialD[(size_t)s * n + v];
        partialD[(size_t)s * n + v] = base;
        base += c;
    }
}

// fill: block (s,r) places its slice's in-range edges using LDS cursors
__global__ __launch_bounds__(256) void fillp_kernel(const int* __restrict__ src,
                                                    const int* __restrict__ dst,
                                                    const float* __restrict__ ns,
                                                    const int* __restrict__ partialD,
                                                    int* __restrict__ esrc,
                                                    float* __restrict__ ew,
                                                    int E, int n) {
    __shared__ int cur[RANGE];
    int tid = threadIdx.x;
    int s = blockIdx.x & (NSLICE - 1);
    int r = blockIdx.x >> 5;
    int v0 = r * RANGE;
    for (int i = tid; i < RANGE; i += 256) {
        int v = v0 + i;
        cur[i] = (v < n) ? partialD[(size_t)s * n + v] : 0;
    }
    __syncthreads();
    int e0 = (int)((long long)E * s / NSLICE);
    int e1 = (int)((long long)E * (s + 1) / NSLICE);
    for (int e = e0 + tid; e < e1; e += 256) {
        int d = dst[e];
        unsigned dd = (unsigned)(d - v0);
        if (dd < RANGE) {
            int p = atomicAdd(&cur[dd], 1);   // LDS atomic
            int sc = src[e];
            esrc[p] = sc;
            ew[p] = ns[sc];
        }
    }
}

// ================= aggregation: one wave per node, half-wave float4 =================
__global__ __launch_bounds__(256) void agg_kernel(const float* __restrict__ x,
                                                  const int* __restrict__ offs,
                                                  const int* __restrict__ esrc,
                                                  const float* __restrict__ ew,
                                                  const float* __restrict__ nd,
                                                  float* __restrict__ m, int n) {
    int gid = blockIdx.x * blockDim.x + threadIdx.x;
    int v = gid >> 6;
    int lane = threadIdx.x & 63;
    int half = lane >> 5;     // 0/1: which edge of the pair
    int c = lane & 31;        // float4 column index
    if (v >= n) return;
    int s0 = offs[v], s1 = offs[v + 1];
    float4 A0 = make_float4(0.f, 0.f, 0.f, 0.f);
    float4 A1 = make_float4(0.f, 0.f, 0.f, 0.f);
    int j = s0 + half;
    for (; j + 2 < s1; j += 4) {      // per half: edges j and j+2
        int e0 = esrc[j], e1 = esrc[j + 2];
        float w0 = ew[j], w1 = ew[j + 2];
        float4 t0 = ((const float4*)(x + (size_t)e0 * FEAT))[c];
        float4 t1 = ((const float4*)(x + (size_t)e1 * FEAT))[c];
        A0.x = fmaf(t0.x, w0, A0.x); A0.y = fmaf(t0.y, w0, A0.y);
        A0.z = fmaf(t0.z, w0, A0.z); A0.w = fmaf(t0.w, w0, A0.w);
        A1.x = fmaf(t1.x, w1, A1.x); A1.y = fmaf(t1.y, w1, A1.y);
        A1.z = fmaf(t1.z, w1, A1.z); A1.w = fmaf(t1.w, w1, A1.w);
    }
    for (; j < s1; j += 2) {
        int e0 = esrc[j];
        float w0 = ew[j];
        float4 t0 = ((const float4*)(x + (size_t)e0 * FEAT))[c];
        A0.x = fmaf(t0.x, w0, A0.x); A0.y = fmaf(t0.y, w0, A0.y);
        A0.z = fmaf(t0.z, w0, A0.z); A0.w = fmaf(t0.w, w0, A0.w);
    }
    A0.x += A1.x; A0.y += A1.y; A0.z += A1.z; A0.w += A1.w;
    // cross-half reduce
    A0.x += __shfl_xor(A0.x, 32);
    A0.y += __shfl_xor(A0.y, 32);
    A0.z += __shfl_xor(A0.z, 32);
    A0.w += __shfl_xor(A0.w, 32);
    if (half == 0) {
        float sc_ = nd[v];
        float4 r;
        r.x = A0.x * sc_; r.y = A0.y * sc_; r.z = A0.z * sc_; r.w = A0.w * sc_;
        ((float4*)(m + (size_t)v * FEAT))[c] = r;
    }
}

// ================= GEMM: 64 rows x 128 cols, 128 threads, 8x8 blocking =================
template<int LAST>
__global__ __launch_bounds__(128) void gemm_kernel(const float* __restrict__ M,
                                                   const float* __restrict__ W,
                                                   const float* __restrict__ bias,
                                                   float* __restrict__ out,
                                                   float* __restrict__ out2, int n) {
    __shared__ float MsT[32][68];   // [k][row], stride 68: 16B-aligned, 2-way banks (free)
    __shared__ float Ws[32][128];
    int tid = threadIdx.x;
    int tx = tid & 15;     // cols 4*tx..+3 and 64+4*tx..+3
    int ty = tid >> 4;     // rows ty*8..+7
    int r0 = blockIdx.x * 64;

    float acc[8][8];
    #pragma unroll
    for (int r = 0; r < 8; ++r)
        #pragma unroll
        for (int i = 0; i < 8; ++i) acc[r][i] = 0.f;

    for (int k0 = 0; k0 < FEAT; k0 += 32) {
        if (k0) __syncthreads();
        // stage W chunk: 32x128 floats = 1024 float4, 8 per thread
        #pragma unroll
        for (int i = 0; i < 8; ++i) {
            int idx = tid + i * 128;
            ((float4*)&Ws[0][0])[idx] = ((const float4*)(W + (size_t)k0 * FEAT))[idx];
        }
        // stage M tile transposed: 64 rows x 32 k = 512 float4, 4 per thread
        #pragma unroll
        for (int jj = 0; jj < 4; ++jj) {
            int i = tid + jj * 128;
            int row = i >> 3, c4 = i & 7;
            int gr = r0 + row;
            float4 v = make_float4(0.f, 0.f, 0.f, 0.f);
            if (gr < n) v = *(const float4*)(M + (size_t)gr * FEAT + k0 + c4 * 4);
            MsT[c4 * 4 + 0][row] = v.x;
            MsT[c4 * 4 + 1][row] = v.y;
            MsT[c4 * 4 + 2][row] = v.z;
            MsT[c4 * 4 + 3][row] = v.w;
        }
        __syncthreads();
        #pragma unroll
        for (int kk = 0; kk < 32; ++kk) {
            float4 a0 = *(const float4*)&MsT[kk][ty * 8];
            float4 a1 = *(const float4*)&MsT[kk][ty * 8 + 4];
            float4 w0 = *(const float4*)&Ws[kk][tx * 4];
            float4 w1 = *(const float4*)&Ws[kk][64 + tx * 4];
            float a[8] = {a0.x, a0.y, a0.z, a0.w, a1.x, a1.y, a1.z, a1.w};
            float w[8] = {w0.x, w0.y, w0.z, w0.w, w1.x, w1.y, w1.z, w1.w};
            #pragma unroll
            for (int r = 0; r < 8; ++r)
                #pragma unroll
                for (int i = 0; i < 8; ++i)
                    acc[r][i] = fmaf(a[r], w[i], acc[r][i]);
        }
    }

    float4 b0 = *(const float4*)&bias[tx * 4];
    float4 b1 = *(const float4*)&bias[64 + tx * 4];
    #pragma unroll
    for (int r = 0; r < 8; ++r) {
        int row = r0 + ty * 8 + r;
        if (row < n) {
            float4 v0, v1;
            v0.x = acc[r][0] + b0.x; v0.y = acc[r][1] + b0.y;
            v0.z = acc[r][2] + b0.z; v0.w = acc[r][3] + b0.w;
            v1.x = acc[r][4] + b1.x; v1.y = acc[r][5] + b1.y;
            v1.z = acc[r][6] + b1.z; v1.w = acc[r][7] + b1.w;
            v0.x = v0.x > 0.f ? v0.x : 0.f; v0.y = v0.y > 0.f ? v0.y : 0.f;
            v0.z = v0.z > 0.f ? v0.z : 0.f; v0.w = v0.w > 0.f ? v0.w : 0.f;
            v1.x = v1.x > 0.f ? v1.x : 0.f; v1.y = v1.y > 0.f ? v1.y : 0.f;
            v1.z = v1.z > 0.f ? v1.z : 0.f; v1.w = v1.w > 0.f ? v1.w : 0.f;
            *(float4*)(out + (size_t)row * FEAT + tx * 4) = v0;
            *(float4*)(out + (size_t)row * FEAT + 64 + tx * 4) = v1;
            if (LAST) {
                float4 c0, c1;
                c0.x = v0.x >= 0.5f ? 1.f : 0.f; c0.y = v0.y >= 0.5f ? 1.f : 0.f;
                c0.z = v0.z >= 0.5f ? 1.f : 0.f; c0.w = v0.w >= 0.5f ? 1.f : 0.f;
                c1.x = v1.x >= 0.5f ? 1.f : 0.f; c1.y = v1.y >= 0.5f ? 1.f : 0.f;
                c1.z = v1.z >= 0.5f ? 1.f : 0.f; c1.w = v1.w >= 0.5f ? 1.f : 0.f;
                *(float4*)(out2 + (size_t)row * FEAT + tx * 4) = c0;
                *(float4*)(out2 + (size_t)row * FEAT + 64 + tx * 4) = c1;
            }
        }
    }
}

extern "C" void kernel_launch(void* const* d_in, const int* in_sizes, int n_in,
                              void* d_out, int out_size, void* d_ws, size_t ws_size,
                              hipStream_t stream) {
    const float* in_feat = (const float*)d_in[0];
    const int*   src     = (const int*)d_in[1];
    const int*   dst     = (const int*)d_in[2];
    const float* W[5] = {(const float*)d_in[3], (const float*)d_in[5], (const float*)d_in[7],
                         (const float*)d_in[9], (const float*)d_in[11]};
    const float* B[5] = {(const float*)d_in[4], (const float*)d_in[6], (const float*)d_in[8],
                         (const float*)d_in[10], (const float*)d_in[12]};
    const int E = in_sizes[1];
    const int N = in_sizes[0] / FEAT;

    // ---- workspace layout ----
    // partialS is dead after reduce_kernel -> esrc/ew alias its region.
    char* ws = (char*)d_ws;
    size_t off = 0;
    auto alloc = [&](size_t bytes) { size_t o = off; off += (bytes + 255) & ~size_t(255); return o; };
    int*   partialD  = (int*)(ws + alloc((size_t)NSLICE * N * 4));   // 6.4 MB
    size_t unionOff  = alloc((size_t)NSLICE * N * 4);                // 6.4 MB union
    int*   partialS  = (int*)(ws + unionOff);
    int*   esrc      = (int*)(ws + unionOff);                        // aliases partialS
    float* ew        = (float*)(ws + unionOff + (((size_t)E * 4 + 255) & ~size_t(255)));
    float* ns        = (float*)(ws + alloc((size_t)N * 4));
    float* nd        = (float*)(ws + alloc((size_t)N * 4));
    int*   offs      = (int*)  (ws + alloc((size_t)(N + 1) * 4));
    int*   deg_in    = (int*)  (ws + alloc((size_t)N * 4));
    int*   blockSums = (int*)  (ws + alloc(4096));
    int*   blockOffs = (int*)  (ws + alloc(4096));

    float* out_h = (float*)d_out;          // m scratch; h5 at the end (in-place gemm5)
    float* out_c = out_h + (size_t)N * FEAT;   // h ping area; threshold at the end

    const int nRanges = (N + RANGE - 1) / RANGE;       // 13
    const int histBlocks = NSLICE * nRanges;           // 416
    const int nb = (N + 1023) / 1024;                  // 49
    const int vb = (N + 255) / 256;

    hist_kernel<<<histBlocks, 256, 0, stream>>>(src, dst, partialS, partialD, E, N);
    reduce_kernel<<<vb, 256, 0, stream>>>(partialS, partialD, deg_in, ns, nd, N);
    scan_partial<<<nb, 256, 0, stream>>>(deg_in, blockSums, N);
    scan_blocksums<<<1, 256, 0, stream>>>(blockSums, blockOffs, nb, offs, N);
    scan_write<<<nb, 256, 0, stream>>>(deg_in, blockOffs, offs, N);
    cursor_kernel<<<vb, 256, 0, stream>>>(partialD, offs, N);
    fillp_kernel<<<histBlocks, 256, 0, stream>>>(src, dst, ns, partialD, esrc, ew, E, N);

    const int agg_blocks = (int)(((size_t)N * 64 + 255) / 256);
    const int gemm_blocks = (N + 63) / 64;

    // m = out_h region, h = out_c region; gemm5 in-place on out_h + threshold to out_c
    const float* x = in_feat;
    for (int l = 0; l < 5; ++l) {
        agg_kernel<<<agg_blocks, 256, 0, stream>>>(x, offs, esrc, ew, nd, out_h, N);
        if (l < 4) {
            gemm_kernel<0><<<gemm_blocks, 128, 0, stream>>>(out_h, W[l], B[l], out_c, nullptr, N);
            x = out_c;
        } else {
            gemm_kernel<1><<<gemm_blocks, 128, 0, stream>>>(out_h, W[l], B[l], out_h, out_c, N);
        }
    }
}

// Round 6
// 633.630 us; speedup vs baseline: 1.5423x; 1.1292x over previous
//
#include <hip/hip_runtime.h>

#define FEAT 128
#define RANGE 12800
#define NSLICE 64

// ---------- hist: src & dst partial histograms in one dispatch, ushort-packed ----------
__global__ __launch_bounds__(256) void hist_kernel(const int* __restrict__ src,
                                                   const int* __restrict__ dst,
                                                   unsigned* __restrict__ partialD,
                                                   unsigned* __restrict__ partialS,
                                                   int E, int NP) {
    __shared__ unsigned hpk[RANGE / 2];
    int per = (NP / RANGE) * NSLICE;
    int b = blockIdx.x;
    int halfsel = b / per;           // 0 = dst histogram, 1 = src histogram
    int q = b % per;
    int r = q / NSLICE;
    int s = q % NSLICE;
    const int* arr = halfsel ? src : dst;
    unsigned* out = halfsel ? partialS : partialD;
    int v0 = r * RANGE;
    int tid = threadIdx.x;
    for (int i = tid; i < RANGE / 2; i += 256) hpk[i] = 0;
    __syncthreads();
    int e0 = (int)((long long)E * s / NSLICE);
    int e1 = (int)((long long)E * (s + 1) / NSLICE);
    for (int e = e0 + tid; e < e1; e += 256) {
        unsigned d = (unsigned)(arr[e] - v0);
        if (d < RANGE) atomicAdd(&hpk[d >> 1], (d & 1) ? 65536u : 1u);
    }
    __syncthreads();
    size_t wbase = ((size_t)s * NP + v0) >> 1;
    for (int i = tid; i < RANGE / 2; i += 256) out[wbase + i] = hpk[i];
}

// ---------- joint scan phase 1: per-node slice-sums (also writes deg_in) ----------
__global__ __launch_bounds__(256) void scanp1_kernel(const unsigned short* __restrict__ pD,
                                                     int* __restrict__ blockSums,
                                                     int* __restrict__ deg_in,
                                                     int NP, int n) {
    __shared__ int buf[256];
    int tid = threadIdx.x;
    int v = blockIdx.x * 256 + tid;
    int ssum = 0;
    #pragma unroll
    for (int s = 0; s < NSLICE; ++s) ssum += pD[(size_t)s * NP + v];
    if (v < n) deg_in[v] = ssum;
    buf[tid] = ssum;
    __syncthreads();
    #pragma unroll
    for (int off = 1; off < 256; off <<= 1) {
        int t = (tid >= off) ? buf[tid - off] : 0;
        __syncthreads();
        buf[tid] += t;
        __syncthreads();
    }
    if (tid == 255) blockSums[blockIdx.x] = buf[255];
}

// ---------- joint scan phase 2: scan block sums (nb <= 256) ----------
__global__ __launch_bounds__(256) void scanp2_kernel(const int* __restrict__ blockSums,
                                                     int* __restrict__ blockOffs, int nb) {
    __shared__ int buf[256];
    int tid = threadIdx.x;
    int v = (tid < nb) ? blockSums[tid] : 0;
    buf[tid] = v;
    __syncthreads();
    #pragma unroll
    for (int off = 1; off < 256; off <<= 1) {
        int t = (tid >= off) ? buf[tid - off] : 0;
        __syncthreads();
        buf[tid] += t;
        __syncthreads();
    }
    if (tid < nb) blockOffs[tid] = buf[tid] - v;
}

// ---------- joint scan phase 3: write per-(node,slice) cursors (v-major) ----------
__global__ __launch_bounds__(256) void scanp3_kernel(const unsigned short* __restrict__ pD,
                                                     const int* __restrict__ blockOffs,
                                                     int* __restrict__ cursorV, int NP) {
    __shared__ int buf[256];
    int tid = threadIdx.x;
    int v = blockIdx.x * 256 + tid;
    int ssum = 0;
    #pragma unroll
    for (int s = 0; s < NSLICE; ++s) ssum += pD[(size_t)s * NP + v];
    buf[tid] = ssum;
    __syncthreads();
    #pragma unroll
    for (int off = 1; off < 256; off <<= 1) {
        int t = (tid >= off) ? buf[tid - off] : 0;
        __syncthreads();
        buf[tid] += t;
        __syncthreads();
    }
    int o = blockOffs[blockIdx.x] + buf[tid] - ssum;
    int* cv = cursorV + (size_t)v * NSLICE;
    #pragma unroll
    for (int s = 0; s < NSLICE; ++s) {
        int val = pD[(size_t)s * NP + v];
        cv[s] = o;
        o += val;
    }
}

// ---------- norms ----------
__global__ void norms_kernel(const unsigned short* __restrict__ pS,
                             const int* __restrict__ deg_in,
                             float* __restrict__ ns, float* __restrict__ nd,
                             int NP, int n) {
    int v = blockIdx.x * blockDim.x + threadIdx.x;
    if (v >= n) return;
    int so = 0;
    #pragma unroll
    for (int s = 0; s < NSLICE; ++s) so += pS[(size_t)s * NP + v];
    int si = deg_in[v];
    ns[v] = 1.0f / sqrtf((float)(so < 1 ? 1 : so));
    nd[v] = 1.0f / sqrtf((float)(si < 1 ? 1 : si));
}

// ---------- prescale: xs = in_feat * ns ----------
__global__ void prescale_kernel(const float* __restrict__ x, const float* __restrict__ ns,
                                float* __restrict__ xs, int n) {
    int i = blockIdx.x * blockDim.x + threadIdx.x;
    if (i >= n * (FEAT / 4)) return;
    int v = i >> 5;
    float w = ns[v];
    float4 t = ((const float4*)x)[i];
    t.x *= w; t.y *= w; t.z *= w; t.w *= w;
    ((float4*)xs)[i] = t;
}

// ---------- extract compact offsets ----------
__global__ void extract_kernel(const int* __restrict__ cursorV, int* __restrict__ offsc, int n) {
    int v = blockIdx.x * blockDim.x + threadIdx.x;
    if (v <= n) offsc[v] = cursorV[(size_t)v * NSLICE];
}

// ---------- fill: place edges via LDS cursors (XCD-swizzled slices) ----------
__global__ __launch_bounds__(256) void fill_kernel(const int* __restrict__ src,
                                                   const int* __restrict__ dst,
                                                   const int* __restrict__ cursorV,
                                                   int* __restrict__ esrc, int E, int NP) {
    __shared__ int cur[RANGE];
    int b = blockIdx.x;
    int r = b / NSLICE;
    int inner = b % NSLICE;
    int s = ((inner & 7) << 3) | (inner >> 3);   // same-XCD blocks get consecutive slices
    int v0 = r * RANGE;
    int tid = threadIdx.x;
    for (int i = tid; i < RANGE; i += 256)
        cur[i] = cursorV[(size_t)(v0 + i) * NSLICE + s];
    __syncthreads();
    int e0 = (int)((long long)E * s / NSLICE);
    int e1 = (int)((long long)E * (s + 1) / NSLICE);
    for (int e = e0 + tid; e < e1; e += 256) {
        unsigned dd = (unsigned)(dst[e] - v0);
        if (dd < RANGE) {
            int p = atomicAdd(&cur[dd], 1);
            esrc[p] = src[e];
        }
    }
}

// ---------- aggregation: pure row-sum, half-wave float4, 8 rows in flight ----------
__global__ __launch_bounds__(256) void agg_kernel(const float* __restrict__ x,
                                                  const int* __restrict__ offs,
                                                  const int* __restrict__ esrc,
                                                  const float* __restrict__ nd,
                                                  float* __restrict__ m, int n) {
    int gid = blockIdx.x * blockDim.x + threadIdx.x;
    int v = gid >> 6;
    int lane = threadIdx.x & 63;
    int half = lane >> 5;
    int c = lane & 31;
    if (v >= n) return;
    int s0 = offs[v], s1 = offs[v + 1];
    float4 A0 = make_float4(0.f, 0.f, 0.f, 0.f);
    float4 A1 = make_float4(0.f, 0.f, 0.f, 0.f);
    float4 A2 = make_float4(0.f, 0.f, 0.f, 0.f);
    float4 A3 = make_float4(0.f, 0.f, 0.f, 0.f);
    int j = s0 + half;
    for (; j + 6 < s1; j += 8) {
        int e0 = esrc[j], e1 = esrc[j + 2], e2 = esrc[j + 4], e3 = esrc[j + 6];
        float4 t0 = ((const float4*)(x + (size_t)e0 * FEAT))[c];
        float4 t1 = ((const float4*)(x + (size_t)e1 * FEAT))[c];
        float4 t2 = ((const float4*)(x + (size_t)e2 * FEAT))[c];
        float4 t3 = ((const float4*)(x + (size_t)e3 * FEAT))[c];
        A0.x += t0.x; A0.y += t0.y; A0.z += t0.z; A0.w += t0.w;
        A1.x += t1.x; A1.y += t1.y; A1.z += t1.z; A1.w += t1.w;
        A2.x += t2.x; A2.y += t2.y; A2.z += t2.z; A2.w += t2.w;
        A3.x += t3.x; A3.y += t3.y; A3.z += t3.z; A3.w += t3.w;
    }
    for (; j < s1; j += 2) {
        int e0 = esrc[j];
        float4 t0 = ((const float4*)(x + (size_t)e0 * FEAT))[c];
        A0.x += t0.x; A0.y += t0.y; A0.z += t0.z; A0.w += t0.w;
    }
    A0.x += A1.x + A2.x + A3.x;
    A0.y += A1.y + A2.y + A3.y;
    A0.z += A1.z + A2.z + A3.z;
    A0.w += A1.w + A2.w + A3.w;
    A0.x += __shfl_xor(A0.x, 32);
    A0.y += __shfl_xor(A0.y, 32);
    A0.z += __shfl_xor(A0.z, 32);
    A0.w += __shfl_xor(A0.w, 32);
    if (half == 0) {
        float sc_ = nd[v];
        float4 r;
        r.x = A0.x * sc_; r.y = A0.y * sc_; r.z = A0.z * sc_; r.w = A0.w * sc_;
        ((float4*)(m + (size_t)v * FEAT))[c] = r;
    }
}

// ---------- GEMM: 64x128 tile, 128 threads, 8x8 blocking ----------
template<int MODE>   // 0: relu*ns (mid layer)   1: last layer (h + threshold)
__global__ __launch_bounds__(128) void gemm_kernel(const float* __restrict__ M,
                                                   const float* __restrict__ W,
                                                   const float* __restrict__ bias,
                                                   const float* __restrict__ nsv,
                                                   float* __restrict__ out,
                                                   float* __restrict__ out2, int n) {
    __shared__ float MsT[32][68];
    __shared__ float Ws[32][128];
    __shared__ float ns_s[64];
    int tid = threadIdx.x;
    int tx = tid & 15;
    int ty = tid >> 4;
    int r0 = blockIdx.x * 64;
    if (MODE == 0 && tid < 64) ns_s[tid] = (r0 + tid < n) ? nsv[r0 + tid] : 1.0f;

    float acc[8][8];
    #pragma unroll
    for (int r = 0; r < 8; ++r)
        #pragma unroll
        for (int i = 0; i < 8; ++i) acc[r][i] = 0.f;

    for (int k0 = 0; k0 < FEAT; k0 += 32) {
        if (k0) __syncthreads();
        #pragma unroll
        for (int i = 0; i < 8; ++i) {
            int idx = tid + i * 128;
            ((float4*)&Ws[0][0])[idx] = ((const float4*)(W + (size_t)k0 * FEAT))[idx];
        }
        #pragma unroll
        for (int jj = 0; jj < 4; ++jj) {
            int i = tid + jj * 128;
            int row = i >> 3, c4 = i & 7;
            int gr = r0 + row;
            float4 v = make_float4(0.f, 0.f, 0.f, 0.f);
            if (gr < n) v = *(const float4*)(M + (size_t)gr * FEAT + k0 + c4 * 4);
            MsT[c4 * 4 + 0][row] = v.x;
            MsT[c4 * 4 + 1][row] = v.y;
            MsT[c4 * 4 + 2][row] = v.z;
            MsT[c4 * 4 + 3][row] = v.w;
        }
        __syncthreads();
        #pragma unroll
        for (int kk = 0; kk < 32; ++kk) {
            float4 a0 = *(const float4*)&MsT[kk][ty * 8];
            float4 a1 = *(const float4*)&MsT[kk][ty * 8 + 4];
            float4 w0 = *(const float4*)&Ws[kk][tx * 4];
            float4 w1 = *(const float4*)&Ws[kk][64 + tx * 4];
            float a[8] = {a0.x, a0.y, a0.z, a0.w, a1.x, a1.y, a1.z, a1.w};
            float w[8] = {w0.x, w0.y, w0.z, w0.w, w1.x, w1.y, w1.z, w1.w};
            #pragma unroll
            for (int r = 0; r < 8; ++r)
                #pragma unroll
                for (int i = 0; i < 8; ++i)
                    acc[r][i] = fmaf(a[r], w[i], acc[r][i]);
        }
    }

    float4 b0 = *(const float4*)&bias[tx * 4];
    float4 b1 = *(const float4*)&bias[64 + tx * 4];
    #pragma unroll
    for (int r = 0; r < 8; ++r) {
        int row = r0 + ty * 8 + r;
        if (row < n) {
            float4 v0, v1;
            v0.x = acc[r][0] + b0.x; v0.y = acc[r][1] + b0.y;
            v0.z = acc[r][2] + b0.z; v0.w = acc[r][3] + b0.w;
            v1.x = acc[r][4] + b1.x; v1.y = acc[r][5] + b1.y;
            v1.z = acc[r][6] + b1.z; v1.w = acc[r][7] + b1.w;
            v0.x = v0.x > 0.f ? v0.x : 0.f; v0.y = v0.y > 0.f ? v0.y : 0.f;
            v0.z = v0.z > 0.f ? v0.z : 0.f; v0.w = v0.w > 0.f ? v0.w : 0.f;
            v1.x = v1.x > 0.f ? v1.x : 0.f; v1.y = v1.y > 0.f ? v1.y : 0.f;
            v1.z = v1.z > 0.f ? v1.z : 0.f; v1.w = v1.w > 0.f ? v1.w : 0.f;
            if (MODE == 0) {
                float sc_ = ns_s[ty * 8 + r];
                v0.x *= sc_; v0.y *= sc_; v0.z *= sc_; v0.w *= sc_;
                v1.x *= sc_; v1.y *= sc_; v1.z *= sc_; v1.w *= sc_;
            }
            *(float4*)(out + (size_t)row * FEAT + tx * 4) = v0;
            *(float4*)(out + (size_t)row * FEAT + 64 + tx * 4) = v1;
            if (MODE == 1) {
                float4 c0, c1;
                c0.x = v0.x >= 0.5f ? 1.f : 0.f; c0.y = v0.y >= 0.5f ? 1.f : 0.f;
                c0.z = v0.z >= 0.5f ? 1.f : 0.f; c0.w = v0.w >= 0.5f ? 1.f : 0.f;
                c1.x = v1.x >= 0.5f ? 1.f : 0.f; c1.y = v1.y >= 0.5f ? 1.f : 0.f;
                c1.z = v1.z >= 0.5f ? 1.f : 0.f; c1.w = v1.w >= 0.5f ? 1.f : 0.f;
                *(float4*)(out2 + (size_t)row * FEAT + tx * 4) = c0;
                *(float4*)(out2 + (size_t)row * FEAT + 64 + tx * 4) = c1;
            }
        }
    }
}

extern "C" void kernel_launch(void* const* d_in, const int* in_sizes, int n_in,
                              void* d_out, int out_size, void* d_ws, size_t ws_size,
                              hipStream_t stream) {
    const float* in_feat = (const float*)d_in[0];
    const int*   src     = (const int*)d_in[1];
    const int*   dst     = (const int*)d_in[2];
    const float* W[5] = {(const float*)d_in[3], (const float*)d_in[5], (const float*)d_in[7],
                         (const float*)d_in[9], (const float*)d_in[11]};
    const float* B[5] = {(const float*)d_in[4], (const float*)d_in[6], (const float*)d_in[8],
                         (const float*)d_in[10], (const float*)d_in[12]};
    const int E = in_sizes[1];
    const int N = in_sizes[0] / FEAT;
    const int NRANGE = (N + RANGE - 1) / RANGE;       // 4
    const int NP = NRANGE * RANGE;                    // 51200
    const size_t MTOT = (size_t)NP * NSLICE;          // 3,276,800

    char* ws = (char*)d_ws;
    size_t off = 0;
    auto alloc = [&](size_t bytes) { size_t o = off; off += (bytes + 255) & ~size_t(255); return o; };
    unsigned* partialD = (unsigned*)(ws + alloc(MTOT * 2));
    size_t    pS_off   = alloc(MTOT * 2);
    unsigned* partialS = (unsigned*)(ws + pS_off);
    int*      esrc     = (int*)(ws + pS_off);          // aliases partialS (dead after norms)
    int*      cursorV  = (int*)(ws + alloc(MTOT * 4));
    int*      deg_in   = (int*)(ws + alloc((size_t)N * 4));
    float*    ns       = (float*)(ws + alloc((size_t)N * 4));
    float*    nd       = (float*)(ws + alloc((size_t)N * 4));
    int*      offsc    = (int*)(ws + alloc((size_t)(N + 1) * 4));
    int*      blockSums = (int*)(ws + alloc(1024));
    int*      blockOffs = (int*)(ws + alloc(1024));

    float* out_h = (float*)d_out;                     // m scratch; h5 at the end
    float* out_c = out_h + (size_t)N * FEAT;          // xs / h-scaled chain; threshold at end

    const int histBlocks = 2 * NRANGE * NSLICE;       // 512
    const int scanBlocks = NP / 256;                  // 200
    const int vb = (N + 255) / 256;

    hist_kernel<<<histBlocks, 256, 0, stream>>>(src, dst, partialD, partialS, E, NP);
    scanp1_kernel<<<scanBlocks, 256, 0, stream>>>((const unsigned short*)partialD,
                                                  blockSums, deg_in, NP, N);
    scanp2_kernel<<<1, 256, 0, stream>>>(blockSums, blockOffs, scanBlocks);
    scanp3_kernel<<<scanBlocks, 256, 0, stream>>>((const unsigned short*)partialD,
                                                  blockOffs, cursorV, NP);
    norms_kernel<<<vb, 256, 0, stream>>>((const unsigned short*)partialS, deg_in, ns, nd, NP, N);
    prescale_kernel<<<(N * 32 + 255) / 256, 256, 0, stream>>>(in_feat, ns, out_c, N);
    extract_kernel<<<(N + 256) / 256, 256, 0, stream>>>(cursorV, offsc, N);
    fill_kernel<<<NRANGE * NSLICE, 256, 0, stream>>>(src, dst, cursorV, esrc, E, NP);

    const int agg_blocks = (int)(((size_t)N * 64 + 255) / 256);
    const int gemm_blocks = (N + 63) / 64;

    for (int l = 0; l < 5; ++l) {
        agg_kernel<<<agg_blocks, 256, 0, stream>>>(out_c, offsc, esrc, nd, out_h, N);
        if (l < 4)
            gemm_kernel<0><<<gemm_blocks, 128, 0, stream>>>(out_h, W[l], B[l], ns, out_c, nullptr, N);
        else
            gemm_kernel<1><<<gemm_blocks, 128, 0, stream>>>(out_h, W[l], B[l], ns, out_h, out_c, N);
    }
}

// Round 7
// 594.869 us; speedup vs baseline: 1.6428x; 1.0652x over previous
//
#include <hip/hip_runtime.h>

#define FEAT 128
#define RANGE 12800
#define NSLICE 64

// ---------- hist: src & dst partial histograms in one dispatch, ushort-packed ----------
__global__ __launch_bounds__(256) void hist_kernel(const int* __restrict__ src,
                                                   const int* __restrict__ dst,
                                                   unsigned* __restrict__ partialD,
                                                   unsigned* __restrict__ partialS,
                                                   int E, int NP) {
    __shared__ unsigned hpk[RANGE / 2];
    int per = (NP / RANGE) * NSLICE;
    int b = blockIdx.x;
    int halfsel = b / per;           // 0 = dst histogram, 1 = src histogram
    int q = b % per;
    int r = q / NSLICE;
    int s = q % NSLICE;
    const int* arr = halfsel ? src : dst;
    unsigned* out = halfsel ? partialS : partialD;
    int v0 = r * RANGE;
    int tid = threadIdx.x;
    for (int i = tid; i < RANGE / 2; i += 256) hpk[i] = 0;
    __syncthreads();
    int e0 = (int)((long long)E * s / NSLICE);
    int e1 = (int)((long long)E * (s + 1) / NSLICE);
    for (int e = e0 + tid; e < e1; e += 256) {
        unsigned d = (unsigned)(arr[e] - v0);
        if (d < RANGE) atomicAdd(&hpk[d >> 1], (d & 1) ? 65536u : 1u);
    }
    __syncthreads();
    size_t wbase = ((size_t)s * NP + v0) >> 1;
    for (int i = tid; i < RANGE / 2; i += 256) out[wbase + i] = hpk[i];
}

// ---------- scan phase 1: per-node slice-sums + deg_in + norms ----------
__global__ __launch_bounds__(256) void scanp1_kernel(const unsigned short* __restrict__ pD,
                                                     const unsigned short* __restrict__ pS,
                                                     int* __restrict__ blockSums,
                                                     float* __restrict__ ns,
                                                     float* __restrict__ nd,
                                                     int NP, int n) {
    __shared__ int buf[256];
    int tid = threadIdx.x;
    int v = blockIdx.x * 256 + tid;
    int ssum = 0, osum = 0;
    #pragma unroll
    for (int s = 0; s < NSLICE; ++s) {
        ssum += pD[(size_t)s * NP + v];
        osum += pS[(size_t)s * NP + v];
    }
    if (v < n) {
        ns[v] = 1.0f / sqrtf((float)(osum < 1 ? 1 : osum));
        nd[v] = 1.0f / sqrtf((float)(ssum < 1 ? 1 : ssum));
    }
    buf[tid] = ssum;
    __syncthreads();
    #pragma unroll
    for (int off = 1; off < 256; off <<= 1) {
        int t = (tid >= off) ? buf[tid - off] : 0;
        __syncthreads();
        buf[tid] += t;
        __syncthreads();
    }
    if (tid == 255) blockSums[blockIdx.x] = buf[255];
}

// ---------- scan phase 2 ----------
__global__ __launch_bounds__(256) void scanp2_kernel(const int* __restrict__ blockSums,
                                                     int* __restrict__ blockOffs, int nb) {
    __shared__ int buf[256];
    int tid = threadIdx.x;
    int v = (tid < nb) ? blockSums[tid] : 0;
    buf[tid] = v;
    __syncthreads();
    #pragma unroll
    for (int off = 1; off < 256; off <<= 1) {
        int t = (tid >= off) ? buf[tid - off] : 0;
        __syncthreads();
        buf[tid] += t;
        __syncthreads();
    }
    if (tid < nb) blockOffs[tid] = buf[tid] - v;
}

// ---------- scan phase 3: per-(node,slice) cursors + compact offsets ----------
__global__ __launch_bounds__(256) void scanp3_kernel(const unsigned short* __restrict__ pD,
                                                     const int* __restrict__ blockOffs,
                                                     int* __restrict__ cursorV,
                                                     int* __restrict__ offsc,
                                                     int NP, int n) {
    __shared__ int buf[256];
    int tid = threadIdx.x;
    int v = blockIdx.x * 256 + tid;
    int ssum = 0;
    #pragma unroll
    for (int s = 0; s < NSLICE; ++s) ssum += pD[(size_t)s * NP + v];
    buf[tid] = ssum;
    __syncthreads();
    #pragma unroll
    for (int off = 1; off < 256; off <<= 1) {
        int t = (tid >= off) ? buf[tid - off] : 0;
        __syncthreads();
        buf[tid] += t;
        __syncthreads();
    }
    int o = blockOffs[blockIdx.x] + buf[tid] - ssum;
    if (v <= n) offsc[v] = o;          // pad nodes have zero edges -> v==n gets total
    int* cv = cursorV + (size_t)v * NSLICE;
    #pragma unroll
    for (int s = 0; s < NSLICE; ++s) {
        int val = pD[(size_t)s * NP + v];
        cv[s] = o;
        o += val;
    }
}

// ---------- prescale: xs = in_feat * ns ----------
__global__ void prescale_kernel(const float* __restrict__ x, const float* __restrict__ ns,
                                float* __restrict__ xs, int n) {
    int i = blockIdx.x * blockDim.x + threadIdx.x;
    if (i >= n * (FEAT / 4)) return;
    int v = i >> 5;
    float w = ns[v];
    float4 t = ((const float4*)x)[i];
    t.x *= w; t.y *= w; t.z *= w; t.w *= w;
    ((float4*)xs)[i] = t;
}

// ---------- fill: place edges via LDS cursors (XCD-swizzled slices) ----------
__global__ __launch_bounds__(256) void fill_kernel(const int* __restrict__ src,
                                                   const int* __restrict__ dst,
                                                   const int* __restrict__ cursorV,
                                                   int* __restrict__ esrc, int E, int NP) {
    __shared__ int cur[RANGE];
    int b = blockIdx.x;
    int r = b / NSLICE;
    int inner = b % NSLICE;
    int s = ((inner & 7) << 3) | (inner >> 3);
    int v0 = r * RANGE;
    int tid = threadIdx.x;
    for (int i = tid; i < RANGE; i += 256)
        cur[i] = cursorV[(size_t)(v0 + i) * NSLICE + s];
    __syncthreads();
    int e0 = (int)((long long)E * s / NSLICE);
    int e1 = (int)((long long)E * (s + 1) / NSLICE);
    for (int e = e0 + tid; e < e1; e += 256) {
        unsigned dd = (unsigned)(dst[e] - v0);
        if (dd < RANGE) {
            int p = atomicAdd(&cur[dd], 1);
            esrc[p] = src[e];
        }
    }
}

// ---------- aggregation: pure row-sum, half-wave float4, 8 rows in flight ----------
__global__ __launch_bounds__(256) void agg_kernel(const float* __restrict__ x,
                                                  const int* __restrict__ offs,
                                                  const int* __restrict__ esrc,
                                                  const float* __restrict__ nd,
                                                  float* __restrict__ m, int n) {
    int gid = blockIdx.x * blockDim.x + threadIdx.x;
    int v = gid >> 6;
    int lane = threadIdx.x & 63;
    int half = lane >> 5;
    int c = lane & 31;
    if (v >= n) return;
    int s0 = offs[v], s1 = offs[v + 1];
    float4 A0 = make_float4(0.f, 0.f, 0.f, 0.f);
    float4 A1 = make_float4(0.f, 0.f, 0.f, 0.f);
    float4 A2 = make_float4(0.f, 0.f, 0.f, 0.f);
    float4 A3 = make_float4(0.f, 0.f, 0.f, 0.f);
    int j = s0 + half;
    for (; j + 6 < s1; j += 8) {
        int e0 = esrc[j], e1 = esrc[j + 2], e2 = esrc[j + 4], e3 = esrc[j + 6];
        float4 t0 = ((const float4*)(x + (size_t)e0 * FEAT))[c];
        float4 t1 = ((const float4*)(x + (size_t)e1 * FEAT))[c];
        float4 t2 = ((const float4*)(x + (size_t)e2 * FEAT))[c];
        float4 t3 = ((const float4*)(x + (size_t)e3 * FEAT))[c];
        A0.x += t0.x; A0.y += t0.y; A0.z += t0.z; A0.w += t0.w;
        A1.x += t1.x; A1.y += t1.y; A1.z += t1.z; A1.w += t1.w;
        A2.x += t2.x; A2.y += t2.y; A2.z += t2.z; A2.w += t2.w;
        A3.x += t3.x; A3.y += t3.y; A3.z += t3.z; A3.w += t3.w;
    }
    for (; j < s1; j += 2) {
        int e0 = esrc[j];
        float4 t0 = ((const float4*)(x + (size_t)e0 * FEAT))[c];
        A0.x += t0.x; A0.y += t0.y; A0.z += t0.z; A0.w += t0.w;
    }
    A0.x += A1.x + A2.x + A3.x;
    A0.y += A1.y + A2.y + A3.y;
    A0.z += A1.z + A2.z + A3.z;
    A0.w += A1.w + A2.w + A3.w;
    A0.x += __shfl_xor(A0.x, 32);
    A0.y += __shfl_xor(A0.y, 32);
    A0.z += __shfl_xor(A0.z, 32);
    A0.w += __shfl_xor(A0.w, 32);
    if (half == 0) {
        float sc_ = nd[v];
        float4 r;
        r.x = A0.x * sc_; r.y = A0.y * sc_; r.z = A0.z * sc_; r.w = A0.w * sc_;
        ((float4*)(m + (size_t)v * FEAT))[c] = r;
    }
}

// ---------- GEMM: 64x128 tile, 256 threads (4 waves), 4x8 blocking ----------
template<int MODE>   // 0: relu*ns (mid layer)   1: last layer (h + threshold)
__global__ __launch_bounds__(256) void gemm_kernel(const float* __restrict__ M,
                                                   const float* __restrict__ W,
                                                   const float* __restrict__ bias,
                                                   const float* __restrict__ nsv,
                                                   float* __restrict__ out,
                                                   float* __restrict__ out2, int n) {
    __shared__ float MsT[32][68];    // [k][row] transposed, stride 68 (16B-aligned)
    __shared__ float Ws[32][128];
    __shared__ float ns_s[64];
    int tid = threadIdx.x;
    int tx = tid & 15;     // cols tx*4..+3 and 64+tx*4..+3
    int ty = tid >> 4;     // rows ty*4..+3  (16 groups x 4 = 64 rows)
    int r0 = blockIdx.x * 64;
    if (MODE == 0 && tid < 64) ns_s[tid] = (r0 + tid < n) ? nsv[r0 + tid] : 1.0f;

    float acc[4][8];
    #pragma unroll
    for (int r = 0; r < 4; ++r)
        #pragma unroll
        for (int i = 0; i < 8; ++i) acc[r][i] = 0.f;

    for (int k0 = 0; k0 < FEAT; k0 += 32) {
        if (k0) __syncthreads();
        // stage W chunk: 1024 float4, 4 per thread
        #pragma unroll
        for (int i = 0; i < 4; ++i) {
            int idx = tid + i * 256;
            ((float4*)&Ws[0][0])[idx] = ((const float4*)(W + (size_t)k0 * FEAT))[idx];
        }
        // stage M tile transposed: 512 float4, 2 per thread
        #pragma unroll
        for (int jj = 0; jj < 2; ++jj) {
            int i = tid + jj * 256;
            int row = i >> 3, c4 = i & 7;
            int gr = r0 + row;
            float4 v = make_float4(0.f, 0.f, 0.f, 0.f);
            if (gr < n) v = *(const float4*)(M + (size_t)gr * FEAT + k0 + c4 * 4);
            MsT[c4 * 4 + 0][row] = v.x;
            MsT[c4 * 4 + 1][row] = v.y;
            MsT[c4 * 4 + 2][row] = v.z;
            MsT[c4 * 4 + 3][row] = v.w;
        }
        __syncthreads();
        #pragma unroll
        for (int kk = 0; kk < 32; ++kk) {
            float4 a4 = *(const float4*)&MsT[kk][ty * 4];
            float4 w0 = *(const float4*)&Ws[kk][tx * 4];
            float4 w1 = *(const float4*)&Ws[kk][64 + tx * 4];
            float a[4] = {a4.x, a4.y, a4.z, a4.w};
            float w[8] = {w0.x, w0.y, w0.z, w0.w, w1.x, w1.y, w1.z, w1.w};
            #pragma unroll
            for (int r = 0; r < 4; ++r)
                #pragma unroll
                for (int i = 0; i < 8; ++i)
                    acc[r][i] = fmaf(a[r], w[i], acc[r][i]);
        }
    }

    float4 b0 = *(const float4*)&bias[tx * 4];
    float4 b1 = *(const float4*)&bias[64 + tx * 4];
    #pragma unroll
    for (int r = 0; r < 4; ++r) {
        int row = r0 + ty * 4 + r;
        if (row < n) {
            float4 v0, v1;
            v0.x = acc[r][0] + b0.x; v0.y = acc[r][1] + b0.y;
            v0.z = acc[r][2] + b0.z; v0.w = acc[r][3] + b0.w;
            v1.x = acc[r][4] + b1.x; v1.y = acc[r][5] + b1.y;
            v1.z = acc[r][6] + b1.z; v1.w = acc[r][7] + b1.w;
            v0.x = v0.x > 0.f ? v0.x : 0.f; v0.y = v0.y > 0.f ? v0.y : 0.f;
            v0.z = v0.z > 0.f ? v0.z : 0.f; v0.w = v0.w > 0.f ? v0.w : 0.f;
            v1.x = v1.x > 0.f ? v1.x : 0.f; v1.y = v1.y > 0.f ? v1.y : 0.f;
            v1.z = v1.z > 0.f ? v1.z : 0.f; v1.w = v1.w > 0.f ? v1.w : 0.f;
            if (MODE == 0) {
                float sc_ = ns_s[ty * 4 + r];
                v0.x *= sc_; v0.y *= sc_; v0.z *= sc_; v0.w *= sc_;
                v1.x *= sc_; v1.y *= sc_; v1.z *= sc_; v1.w *= sc_;
            }
            *(float4*)(out + (size_t)row * FEAT + tx * 4) = v0;
            *(float4*)(out + (size_t)row * FEAT + 64 + tx * 4) = v1;
            if (MODE == 1) {
                float4 c0, c1;
                c0.x = v0.x >= 0.5f ? 1.f : 0.f; c0.y = v0.y >= 0.5f ? 1.f : 0.f;
                c0.z = v0.z >= 0.5f ? 1.f : 0.f; c0.w = v0.w >= 0.5f ? 1.f : 0.f;
                c1.x = v1.x >= 0.5f ? 1.f : 0.f; c1.y = v1.y >= 0.5f ? 1.f : 0.f;
                c1.z = v1.z >= 0.5f ? 1.f : 0.f; c1.w = v1.w >= 0.5f ? 1.f : 0.f;
                *(float4*)(out2 + (size_t)row * FEAT + tx * 4) = c0;
                *(float4*)(out2 + (size_t)row * FEAT + 64 + tx * 4) = c1;
            }
        }
    }
}

extern "C" void kernel_launch(void* const* d_in, const int* in_sizes, int n_in,
                              void* d_out, int out_size, void* d_ws, size_t ws_size,
                              hipStream_t stream) {
    const float* in_feat = (const float*)d_in[0];
    const int*   src     = (const int*)d_in[1];
    const int*   dst     = (const int*)d_in[2];
    const float* W[5] = {(const float*)d_in[3], (const float*)d_in[5], (const float*)d_in[7],
                         (const float*)d_in[9], (const float*)d_in[11]};
    const float* B[5] = {(const float*)d_in[4], (const float*)d_in[6], (const float*)d_in[8],
                         (const float*)d_in[10], (const float*)d_in[12]};
    const int E = in_sizes[1];
    const int N = in_sizes[0] / FEAT;
    const int NRANGE = (N + RANGE - 1) / RANGE;       // 4
    const int NP = NRANGE * RANGE;                    // 51200
    const size_t MTOT = (size_t)NP * NSLICE;          // 3,276,800

    char* ws = (char*)d_ws;
    size_t off = 0;
    auto alloc = [&](size_t bytes) { size_t o = off; off += (bytes + 255) & ~size_t(255); return o; };
    unsigned* partialD = (unsigned*)(ws + alloc(MTOT * 2));
    size_t    pS_off   = alloc(MTOT * 2);
    unsigned* partialS = (unsigned*)(ws + pS_off);
    int*      esrc     = (int*)(ws + pS_off);          // aliases partialS (dead after scanp1)
    int*      cursorV  = (int*)(ws + alloc(MTOT * 4));
    float*    ns       = (float*)(ws + alloc((size_t)N * 4));
    float*    nd       = (float*)(ws + alloc((size_t)N * 4));
    int*      offsc    = (int*)(ws + alloc((size_t)(N + 1) * 4));
    int*      blockSums = (int*)(ws + alloc(1024));
    int*      blockOffs = (int*)(ws + alloc(1024));

    float* out_h = (float*)d_out;                     // m scratch; h5 at the end
    float* out_c = out_h + (size_t)N * FEAT;          // xs / scaled-h chain; threshold at end

    const int histBlocks = 2 * NRANGE * NSLICE;       // 512
    const int scanBlocks = NP / 256;                  // 200
    hist_kernel<<<histBlocks, 256, 0, stream>>>(src, dst, partialD, partialS, E, NP);
    scanp1_kernel<<<scanBlocks, 256, 0, stream>>>((const unsigned short*)partialD,
                                                  (const unsigned short*)partialS,
                                                  blockSums, ns, nd, NP, N);
    scanp2_kernel<<<1, 256, 0, stream>>>(blockSums, blockOffs, scanBlocks);
    scanp3_kernel<<<scanBlocks, 256, 0, stream>>>((const unsigned short*)partialD,
                                                  blockOffs, cursorV, offsc, NP, N);
    prescale_kernel<<<(N * 32 + 255) / 256, 256, 0, stream>>>(in_feat, ns, out_c, N);
    fill_kernel<<<NRANGE * NSLICE, 256, 0, stream>>>(src, dst, cursorV, esrc, E, NP);

    const int agg_blocks = (int)(((size_t)N * 64 + 255) / 256);
    const int gemm_blocks = (N + 63) / 64;

    for (int l = 0; l < 5; ++l) {
        agg_kernel<<<agg_blocks, 256, 0, stream>>>(out_c, offsc, esrc, nd, out_h, N);
        if (l < 4)
            gemm_kernel<0><<<gemm_blocks, 256, 0, stream>>>(out_h, W[l], B[l], ns, out_c, nullptr, N);
        else
            gemm_kernel<1><<<gemm_blocks, 256, 0, stream>>>(out_h, W[l], B[l], ns, out_h, out_c, N);
    }
}